// Round 13
// baseline (174.855 us; speedup 1.0000x reference)
//
#include <hip/hip_runtime.h>
#include <math.h>

#define P_ 1936   // 44*44
#define EPS_ 1e-5f

typedef __attribute__((ext_vector_type(8))) short bf16x8;
typedef __attribute__((ext_vector_type(4))) float f32x4;
typedef __attribute__((ext_vector_type(4))) ushort u16x4;

__device__ __forceinline__ ushort f2bf(float f) {
    union { float f; unsigned u; } v; v.f = f;
    unsigned u = v.u;
    return (ushort)((u + 0x7FFFu + ((u >> 16) & 1u)) >> 16);
}
__device__ __forceinline__ float bf2f(ushort h) {
    union { unsigned u; float f; } v; v.u = (unsigned)h << 16;
    return v.f;
}

__device__ __forceinline__ void bn_coef(const float* stats, const float* g,
                                        const float* be, int ch, float inv_n,
                                        float& sc, float& sh) {
    float sum = stats[ch*2], sq = stats[ch*2+1];
    float mu = sum * inv_n;
    float var = sq * inv_n - mu*mu;
    float r = rsqrtf(var + EPS_);
    sc = g[ch] * r;
    sh = be[ch] - mu * sc;
}

// ---------------- k_setup: weight packs + input prep + zero stats ----------------
__global__ __launch_bounds__(256) void k_setup(const float* __restrict__ whc,
                                               const float* __restrict__ whf,
                                               const float* __restrict__ ws2,
                                               const float* __restrict__ wd1,
                                               const float* __restrict__ ws1,
                                               const float* __restrict__ rgb,
                                               const float* __restrict__ depth,
                                               ushort* __restrict__ wpck,
                                               ushort* __restrict__ a2,
                                               ushort* __restrict__ a3,
                                               ushort* __restrict__ apck1,
                                               ushort* __restrict__ xp,
                                               ushort* __restrict__ depthb,
                                               float* __restrict__ dcor_part,
                                               float* __restrict__ stats) {
    __shared__ float r8[8];
    const int bx = blockIdx.x, t = threadIdx.x;
    if (bx < 2808) {
        if (bx == 0 && t < 192) stats[t] = 0.f;
        int idx = bx * 256 + t;
        if (idx < 147456) {
            const float* src = (idx < 73728) ? whc : whf;
            int j = (idx < 73728) ? idx : idx - 73728;
            int kk = j / 8192, rem = j - kk * 8192;
            int o = rem >> 7, c = rem & 127;
            wpck[(idx < 73728 ? 0 : 73728) + (kk * 64 + o) * 128 + c] =
                f2bf(src[(size_t)(o * 128 + c) * 9 + kk]);
        } else if (idx < 156672) {
            int j = idx - 147456;
            int kk = j >> 10, rem = j & 1023, o = rem >> 5, c = rem & 31;
            a2[j] = f2bf(ws2[((size_t)o*32 + c)*9 + kk]);
            a3[j] = f2bf(wd1[((size_t)c*32 + o)*9 + (8 - kk)]);
        } else if (idx < 718848) {
            int j = idx - 156672;
            int m = j / 1952, p = j - m*1952;
            int o = m / 9, kk = m - o*9;
            apck1[j] = (p < P_) ? f2bf(ws1[((size_t)o*P_ + p)*9 + kk]) : (ushort)0;
        }
        return;
    }
    const int j = bx - 2808;
    const int g8 = j & 7, b = (j >> 3) & 15, q = j >> 7;
    const int c0 = g8 * 8;
    const float* rsrc = rgb   + ((size_t)b*64 + c0)*P_;
    const float* dsrc = depth + ((size_t)b*64 + c0)*P_;
    ushort* xr = xp + ((size_t)(b*16 + g8))*2300*8;
    ushort* xd = xp + ((size_t)(b*16 + 8 + g8))*2300*8;
    if (t < 8) r8[t] = 0.f;
    __syncthreads();
    float dc[8];
    #pragma unroll
    for (int e = 0; e < 8; ++e) dc[e] = 0.f;

    const int pbase = q * 575;
    for (int pos = pbase + t; pos < pbase + 575; pos += 256) {
        int y1 = pos / 50, x1 = pos - y1*50;
        uint4 vr = {0u,0u,0u,0u}, vd = {0u,0u,0u,0u};
        if (y1 >= 1 && y1 <= 44 && x1 >= 1 && x1 <= 44) {
            int p = (y1-1)*44 + (x1-1);
            ushort hr[8], hd[8];
            #pragma unroll
            for (int e = 0; e < 8; ++e) {
                float fr = rsrc[(size_t)e*P_ + p];
                float fd = dsrc[(size_t)e*P_ + p];
                dc[e] = fmaf(fr, fd, dc[e]);
                hr[e] = f2bf(fr); hd[e] = f2bf(fd);
            }
            vr.x = hr[0] | ((unsigned)hr[1] << 16); vr.y = hr[2] | ((unsigned)hr[3] << 16);
            vr.z = hr[4] | ((unsigned)hr[5] << 16); vr.w = hr[6] | ((unsigned)hr[7] << 16);
            vd.x = hd[0] | ((unsigned)hd[1] << 16); vd.y = hd[2] | ((unsigned)hd[3] << 16);
            vd.z = hd[4] | ((unsigned)hd[5] << 16); vd.w = hd[6] | ((unsigned)hd[7] << 16);
        }
        *(uint4*)(xr + (size_t)pos*8) = vr;
        *(uint4*)(xd + (size_t)pos*8) = vd;
    }
    for (int idx = q*976 + t; idx < q*976 + 976; idx += 256) {
        int e = idx / 488, jj = idx - e*488;
        u16x4 h = {0,0,0,0};
        if (jj < 484) {
            float4 f4 = *(const float4*)(dsrc + (size_t)e*P_ + jj*4);
            h[0] = f2bf(f4.x); h[1] = f2bf(f4.y); h[2] = f2bf(f4.z); h[3] = f2bf(f4.w);
        }
        *(u16x4*)(depthb + ((size_t)(b*64 + c0 + e))*1952 + jj*4) = h;
    }
    #pragma unroll
    for (int e = 0; e < 8; ++e) {
        float v = dc[e];
        #pragma unroll
        for (int off = 32; off > 0; off >>= 1) v += __shfl_down(v, off, 64);
        if ((t & 63) == 0) atomicAdd(&r8[e], v);
    }
    __syncthreads();
    if (t < 8) dcor_part[q*1024 + b*64 + c0 + t] = r8[t];
}

// ---------------- k_front: hcconv og-split (352) + Umfma (288) + MLP (16) ----------------
__global__ __launch_bounds__(256) void k_front(const ushort* __restrict__ xp,
                                               const ushort* __restrict__ wt,
                                               const float* __restrict__ bhc,
                                               ushort* __restrict__ hcp,
                                               const ushort* __restrict__ apck1,
                                               const ushort* __restrict__ depthb,
                                               ushort* __restrict__ upck,
                                               const float* __restrict__ dcor_part,
                                               const float* __restrict__ wl1,
                                               const float* __restrict__ bl1,
                                               const float* __restrict__ wl2,
                                               const float* __restrict__ bl2,
                                               float* __restrict__ catt) {
    __shared__ ushort lds[9616];
    __shared__ float mlpb[80];
    const int bx = blockIdx.x, t = threadIdx.x;
    if (bx < 352) {
        const int rt = bx % 11, og = (bx / 11) & 1, b = bx / 22;
        const int w = t >> 6, lane = t & 63, lr = lane & 15, lg = lane >> 4;
        const int r0 = rt * 4;
        f32x4 acc[2][3];
        #pragma unroll
        for (int mf = 0; mf < 2; ++mf)
            #pragma unroll
            for (int nf = 0; nf < 3; ++nf)
                acc[mf][nf] = (f32x4){0.f, 0.f, 0.f, 0.f};

        for (int s = 0; s < 4; ++s) {
            __syncthreads();
            const ushort* gsrc = xp + ((size_t)(b*16 + s*4))*2300*8;
            for (int u = t; u < 1200; u += 256) {
                int cg = u / 300, rem = u - cg*300;
                int rr = rem / 50, xx = rem - rr*50;
                uint4 v = *(const uint4*)(gsrc + (((size_t)cg*46 + (r0+rr))*50 + xx)*8);
                *(uint4*)(lds + (size_t)u*8) = v;
            }
            __syncthreads();
            const int abase = s*32 + lg*8;
            #pragma unroll
            for (int kk = 0; kk < 9; ++kk) {
                bf16x8 af[2];
                #pragma unroll
                for (int mf = 0; mf < 2; ++mf)
                    af[mf] = *(const bf16x8*)(wt + (size_t)(kk*64 + og*32 + mf*16 + lr)*128 + abase);
                const int ky = kk / 3, kx = kk - ky*3;
                #pragma unroll
                for (int nf = 0; nf < 3; ++nf) {
                    bf16x8 bf = *(const bf16x8*)&lds[((lg*6 + (w + ky))*50 + (nf*16 + lr + kx))*8];
                    #pragma unroll
                    for (int mf = 0; mf < 2; ++mf)
                        acc[mf][nf] = __builtin_amdgcn_mfma_f32_16x16x32_bf16(af[mf], bf, acc[mf][nf], 0, 0, 0);
                }
            }
        }
        const int y = r0 + w;
        #pragma unroll
        for (int nf = 0; nf < 3; ++nf) {
            int x = nf*16 + lr;
            if (x < 44) {
                #pragma unroll
                for (int mf = 0; mf < 2; ++mf) {
                    u16x4 pk;
                    #pragma unroll
                    for (int i = 0; i < 4; ++i) {
                        int ol = og*32 + mf*16 + lg*4 + i;
                        pk[i] = f2bf(fmaxf(acc[mf][nf][i] + bhc[ol], 0.f));
                    }
                    int g = og*4 + mf*2 + (lg >> 1);
                    *(u16x4*)(hcp + (((size_t)(b*8 + g)*46 + (y+1))*50 + (x+1))*8 + (lg&1)*4) = pk;
                }
            }
        }
        return;
    }
    const int j = bx - 352;
    const int mt = j % 19, b = j / 19;
    if (mt == 18) {
        float* dcs = mlpb;       // 64
        float* h   = mlpb + 64;  // 16
        if (t < 64) dcs[t] = dcor_part[b*64 + t] + dcor_part[1024 + b*64 + t]
                           + dcor_part[2048 + b*64 + t] + dcor_part[3072 + b*64 + t];
        __syncthreads();
        if (t < 16) {
            float a = bl1[t];
            #pragma unroll 8
            for (int c = 0; c < 64; ++c) a = fmaf(dcs[c], wl1[t*64 + c], a);
            h[t] = fmaxf(a, 0.f);
        }
        __syncthreads();
        if (t < 64) {
            float m = bl2[t];
            #pragma unroll
            for (int jj = 0; jj < 16; ++jj) m = fmaf(h[jj], wl2[t*16 + jj], m);
            catt[b*64 + t] = 1.f / (1.f + expf(-2.f*m));
        }
        return;
    }
    const int nt = t >> 6, lane = t & 63, lr = lane & 15, lg = lane >> 4;
    f32x4 acc = (f32x4){0.f, 0.f, 0.f, 0.f};
    const ushort* ap = apck1 + (size_t)(mt*16 + lr)*1952 + lg*8;
    const ushort* bp = depthb + ((size_t)(b*64) + nt*16 + lr)*1952 + lg*8;
    #pragma unroll 4
    for (int ks = 0; ks < 61; ++ks) {
        bf16x8 af = *(const bf16x8*)(ap + ks*32);
        bf16x8 bf = *(const bf16x8*)(bp + ks*32);
        acc = __builtin_amdgcn_mfma_f32_16x16x32_bf16(af, bf, acc, 0, 0, 0);
    }
    #pragma unroll
    for (int i = 0; i < 4; ++i) {
        int m = mt*16 + lg*4 + i;
        int o = m / 9, kk = m - o*9;
        upck[((size_t)(b*9 + kk)*32 + o)*64 + nt*16 + lr] = f2bf(acc[i]);
    }
}

// ---------------- conv1 MFMA: rgb(64ch) x U -> z1p bf16 [b][cg4][42][48][8] + stats ----------------
__global__ __launch_bounds__(256) void k_conv1_mfma(const ushort* __restrict__ xp,
                                                    const ushort* __restrict__ upck,
                                                    const float* __restrict__ bs1,
                                                    ushort* __restrict__ z1p,
                                                    float* __restrict__ stats) {
    __shared__ ushort lds[8*6*50*8 + 32];
    __shared__ float ssum[32], ssq[32];
    const int rt = blockIdx.x, b = blockIdx.y, t = threadIdx.x;
    const int w = t >> 6, lane = t & 63, lr = lane & 15, lg = lane >> 4;
    const int r0 = rt * 4;
    if (t < 32) { ssum[t] = 0.f; ssq[t] = 0.f; }
    f32x4 acc[2][3];
    #pragma unroll
    for (int mf = 0; mf < 2; ++mf)
        #pragma unroll
        for (int nf = 0; nf < 3; ++nf)
            acc[mf][nf] = (f32x4){0.f, 0.f, 0.f, 0.f};

    const ushort* gsrc = xp + (size_t)b*16*2300*8;   // rgb groups 0..7
    for (int u = t; u < 2400; u += 256) {
        int cg = u / 300, rem = u - cg*300;
        int rr = rem / 50, xx = rem - rr*50;
        int y1 = min(r0 + 1 + rr, 45);
        *(uint4*)(lds + (size_t)u*8) = *(const uint4*)(gsrc + (((size_t)cg*46 + y1)*50 + xx)*8);
    }
    __syncthreads();
    #pragma unroll
    for (int s = 0; s < 2; ++s) {
        #pragma unroll
        for (int kk = 0; kk < 9; ++kk) {
            bf16x8 af[2];
            #pragma unroll
            for (int mf = 0; mf < 2; ++mf)
                af[mf] = *(const bf16x8*)(upck + ((size_t)(b*9 + kk)*32 + mf*16 + lr)*64 + s*32 + lg*8);
            const int ky = kk / 3, kx = kk - ky*3;
            #pragma unroll
            for (int nf = 0; nf < 3; ++nf) {
                bf16x8 bv = *(const bf16x8*)&lds[(((s*4 + lg)*6 + (w + ky))*50 + (nf*16 + lr + kx + 1))*8];
                #pragma unroll
                for (int mf = 0; mf < 2; ++mf)
                    acc[mf][nf] = __builtin_amdgcn_mfma_f32_16x16x32_bf16(af[mf], bv, acc[mf][nf], 0, 0, 0);
            }
        }
    }
    const int y = r0 + w;
    const int cb = lg*4;
    if (y < 42) {
        float ls[2][4], lq[2][4], br[2][4];
        #pragma unroll
        for (int mf = 0; mf < 2; ++mf)
            #pragma unroll
            for (int i = 0; i < 4; ++i) {
                ls[mf][i] = 0.f; lq[mf][i] = 0.f;
                br[mf][i] = bs1[mf*16 + cb + i];
            }
        #pragma unroll
        for (int nf = 0; nf < 3; ++nf) {
            int x = nf*16 + lr;
            bool xv = (x < 42);
            #pragma unroll
            for (int mf = 0; mf < 2; ++mf) {
                u16x4 pk;
                #pragma unroll
                for (int i = 0; i < 4; ++i) {
                    float v = acc[mf][nf][i] + br[mf][i];
                    if (xv) { ls[mf][i] += v; lq[mf][i] = fmaf(v, v, lq[mf][i]); }
                    pk[i] = f2bf(v);
                }
                if (xv) {
                    int cg1 = mf*2 + (lg >> 1);
                    *(u16x4*)(z1p + ((((size_t)b*4 + cg1)*42 + y)*48 + x)*8 + (lg&1)*4) = pk;
                }
            }
        }
        #pragma unroll
        for (int mf = 0; mf < 2; ++mf)
            #pragma unroll
            for (int i = 0; i < 4; ++i) {
                float s0 = ls[mf][i], q0 = lq[mf][i];
                #pragma unroll
                for (int m = 1; m < 16; m <<= 1) { s0 += __shfl_xor(s0, m, 64); q0 += __shfl_xor(q0, m, 64); }
                if (lr == 0) { atomicAdd(&ssum[mf*16 + cb + i], s0); atomicAdd(&ssq[mf*16 + cb + i], q0); }
            }
    }
    __syncthreads();
    if (t < 32) { atomicAdd(&stats[t*2], ssum[t]); atomicAdd(&stats[t*2+1], ssq[t]); }
}

// ---------------- conv2 MFMA: relu(bn1(z1)) x ws2 -> z2p bf16 padded [b][cg4][46][48][8] + stats ----------------
__global__ __launch_bounds__(256) void k_conv2_mfma(const ushort* __restrict__ z1p,
                                                    const ushort* __restrict__ apck,
                                                    const float* __restrict__ bs2,
                                                    const float* __restrict__ g1,
                                                    const float* __restrict__ be1,
                                                    const float* __restrict__ statsIn,
                                                    ushort* __restrict__ z2p,
                                                    float* __restrict__ statsOut) {
    __shared__ ushort lds[4*6*48*8 + 32];
    __shared__ float sc[32], sh[32], ssum[32], ssq[32];
    const int rt = blockIdx.x, b = blockIdx.y, t = threadIdx.x;
    const int w = t >> 6, lane = t & 63, lr = lane & 15, lg = lane >> 4;
    const int r0 = rt * 4;
    if (t < 32) {
        bn_coef(statsIn, g1, be1, t, 1.f/28224.f, sc[t], sh[t]);
        ssum[t] = 0.f; ssq[t] = 0.f;
    }
    __syncthreads();
    f32x4 acc[2][3];
    #pragma unroll
    for (int mf = 0; mf < 2; ++mf)
        #pragma unroll
        for (int nf = 0; nf < 3; ++nf)
            acc[mf][nf] = (f32x4){0.f, 0.f, 0.f, 0.f};

    for (int u = t; u < 1152; u += 256) {
        int cg = u / 288, rem = u - cg*288;
        int rr = rem / 48, xx = rem - rr*48;
        uint4 raw = *(const uint4*)(z1p + ((((size_t)b*4 + cg)*42 + (r0 + rr))*48 + xx)*8);
        unsigned arr[4] = {raw.x, raw.y, raw.z, raw.w};
        ushort h[8];
        #pragma unroll
        for (int e = 0; e < 8; ++e) {
            ushort hv = (e & 1) ? (ushort)(arr[e>>1] >> 16) : (ushort)(arr[e>>1] & 0xffffu);
            float f = fmaxf(fmaf(bf2f(hv), sc[cg*8 + e], sh[cg*8 + e]), 0.f);
            h[e] = f2bf(f);
        }
        uint4 v;
        v.x = h[0] | ((unsigned)h[1] << 16);
        v.y = h[2] | ((unsigned)h[3] << 16);
        v.z = h[4] | ((unsigned)h[5] << 16);
        v.w = h[6] | ((unsigned)h[7] << 16);
        *(uint4*)(lds + (size_t)u*8) = v;
    }
    __syncthreads();
    #pragma unroll
    for (int kk = 0; kk < 9; ++kk) {
        bf16x8 af[2];
        #pragma unroll
        for (int mf = 0; mf < 2; ++mf)
            af[mf] = *(const bf16x8*)(apck + (size_t)(kk*32 + mf*16 + lr)*32 + lg*8);
        const int ky = kk / 3, kx = kk - ky*3;
        #pragma unroll
        for (int nf = 0; nf < 3; ++nf) {
            bf16x8 bv = *(const bf16x8*)&lds[((lg*6 + (w + ky))*48 + (nf*16 + lr + kx))*8];
            #pragma unroll
            for (int mf = 0; mf < 2; ++mf)
                acc[mf][nf] = __builtin_amdgcn_mfma_f32_16x16x32_bf16(af[mf], bv, acc[mf][nf], 0, 0, 0);
        }
    }
    const int y = r0 + w;   // 0..39
    const int cb = lg*4;
    {
        float ls[2][4], lq[2][4], br[2][4];
        #pragma unroll
        for (int mf = 0; mf < 2; ++mf)
            #pragma unroll
            for (int i = 0; i < 4; ++i) {
                ls[mf][i] = 0.f; lq[mf][i] = 0.f;
                br[mf][i] = bs2[mf*16 + cb + i];
            }
        #pragma unroll
        for (int nf = 0; nf < 3; ++nf) {
            int x = nf*16 + lr;
            bool xv = (x < 40);
            #pragma unroll
            for (int mf = 0; mf < 2; ++mf) {
                u16x4 pk;
                #pragma unroll
                for (int i = 0; i < 4; ++i) {
                    float v = acc[mf][nf][i] + br[mf][i];
                    if (xv) { ls[mf][i] += v; lq[mf][i] = fmaf(v, v, lq[mf][i]); }
                    pk[i] = f2bf(v);
                }
                if (xv) {
                    int cg1 = mf*2 + (lg >> 1);
                    *(u16x4*)(z2p + ((((size_t)b*4 + cg1)*46 + (y+2))*48 + (x+2))*8 + (lg&1)*4) = pk;
                }
            }
        }
        #pragma unroll
        for (int mf = 0; mf < 2; ++mf)
            #pragma unroll
            for (int i = 0; i < 4; ++i) {
                float s0 = ls[mf][i], q0 = lq[mf][i];
                #pragma unroll
                for (int m = 1; m < 16; m <<= 1) { s0 += __shfl_xor(s0, m, 64); q0 += __shfl_xor(q0, m, 64); }
                if (lr == 0) { atomicAdd(&ssum[mf*16 + cb + i], s0); atomicAdd(&ssq[mf*16 + cb + i], q0); }
            }
    }
    __syncthreads();
    if (t < 32) { atomicAdd(&statsOut[t*2], ssum[t]); atomicAdd(&statsOut[t*2+1], ssq[t]); }
}

// ---------------- dconv1 MFMA: relu(bn2(z2)) *T wd1 -> z3p bf16 padded + stats ----------------
__global__ __launch_bounds__(256) void k_dconv1_mfma(const ushort* __restrict__ z2p,
                                                     const ushort* __restrict__ apck,
                                                     const float* __restrict__ bd1,
                                                     const float* __restrict__ g2,
                                                     const float* __restrict__ be2,
                                                     const float* __restrict__ statsIn,
                                                     ushort* __restrict__ z3p,
                                                     float* __restrict__ statsOut) {
    __shared__ ushort lds[4*6*48*8 + 32];
    __shared__ float sc[32], sh[32], ssum[32], ssq[32];
    const int rt = blockIdx.x, b = blockIdx.y, t = threadIdx.x;
    const int w = t >> 6, lane = t & 63, lr = lane & 15, lg = lane >> 4;
    const int r0 = rt * 4;
    if (t < 32) {
        bn_coef(statsIn, g2, be2, t, 1.f/25600.f, sc[t], sh[t]);
        ssum[t] = 0.f; ssq[t] = 0.f;
    }
    __syncthreads();
    f32x4 acc[2][3];
    #pragma unroll
    for (int mf = 0; mf < 2; ++mf)
        #pragma unroll
        for (int nf = 0; nf < 3; ++nf)
            acc[mf][nf] = (f32x4){0.f, 0.f, 0.f, 0.f};

    for (int u = t; u < 1152; u += 256) {
        int cg = u / 288, rem = u - cg*288;
        int rr = rem / 48, xx = rem - rr*48;
        int row = r0 + rr;
        uint4 v = {0u,0u,0u,0u};
        if (row >= 2 && row <= 41 && xx >= 2 && xx <= 41) {
            uint4 raw = *(const uint4*)(z2p + ((((size_t)b*4 + cg)*46 + row)*48 + xx)*8);
            unsigned arr[4] = {raw.x, raw.y, raw.z, raw.w};
            ushort h[8];
            #pragma unroll
            for (int e = 0; e < 8; ++e) {
                ushort hv = (e & 1) ? (ushort)(arr[e>>1] >> 16) : (ushort)(arr[e>>1] & 0xffffu);
                float f = fmaxf(fmaf(bf2f(hv), sc[cg*8 + e], sh[cg*8 + e]), 0.f);
                h[e] = f2bf(f);
            }
            v.x = h[0] | ((unsigned)h[1] << 16);
            v.y = h[2] | ((unsigned)h[3] << 16);
            v.z = h[4] | ((unsigned)h[5] << 16);
            v.w = h[6] | ((unsigned)h[7] << 16);
        }
        *(uint4*)(lds + (size_t)u*8) = v;
    }
    __syncthreads();
    #pragma unroll
    for (int kk = 0; kk < 9; ++kk) {
        bf16x8 af[2];
        #pragma unroll
        for (int mf = 0; mf < 2; ++mf)
            af[mf] = *(const bf16x8*)(apck + (size_t)(kk*32 + mf*16 + lr)*32 + lg*8);
        const int ky = kk / 3, kx = kk - ky*3;
        #pragma unroll
        for (int nf = 0; nf < 3; ++nf) {
            bf16x8 bv = *(const bf16x8*)&lds[((lg*6 + (w + ky))*48 + (nf*16 + lr + kx))*8];
            #pragma unroll
            for (int mf = 0; mf < 2; ++mf)
                acc[mf][nf] = __builtin_amdgcn_mfma_f32_16x16x32_bf16(af[mf], bv, acc[mf][nf], 0, 0, 0);
        }
    }
    const int y = r0 + w;
    const int cb = lg*4;
    if (y < 42) {
        float ls[2][4], lq[2][4], br[2][4];
        #pragma unroll
        for (int mf = 0; mf < 2; ++mf)
            #pragma unroll
            for (int i = 0; i < 4; ++i) {
                ls[mf][i] = 0.f; lq[mf][i] = 0.f;
                br[mf][i] = bd1[mf*16 + cb + i];
            }
        #pragma unroll
        for (int nf = 0; nf < 3; ++nf) {
            int x = nf*16 + lr;
            bool xv = (x < 42);
            #pragma unroll
            for (int mf = 0; mf < 2; ++mf) {
                u16x4 pk;
                #pragma unroll
                for (int i = 0; i < 4; ++i) {
                    float v = acc[mf][nf][i] + br[mf][i];
                    if (xv) { ls[mf][i] += v; lq[mf][i] = fmaf(v, v, lq[mf][i]); }
                    pk[i] = f2bf(v);
                }
                if (xv) {
                    int cg1 = mf*2 + (lg >> 1);
                    *(u16x4*)(z3p + ((((size_t)b*4 + cg1)*46 + (y+2))*48 + (x+2))*8 + (lg&1)*4) = pk;
                }
            }
        }
        #pragma unroll
        for (int mf = 0; mf < 2; ++mf)
            #pragma unroll
            for (int i = 0; i < 4; ++i) {
                float s0 = ls[mf][i], q0 = lq[mf][i];
                #pragma unroll
                for (int m = 1; m < 16; m <<= 1) { s0 += __shfl_xor(s0, m, 64); q0 += __shfl_xor(q0, m, 64); }
                if (lr == 0) { atomicAdd(&ssum[mf*16 + cb + i], s0); atomicAdd(&ssq[mf*16 + cb + i], q0); }
            }
    }
    __syncthreads();
    if (t < 32) { atomicAdd(&statsOut[t*2], ssum[t]); atomicAdd(&statsOut[t*2+1], ssq[t]); }
}

// ---------------- final conv MFMA with inlined dconv2 (satt computed in LDS) ----------------
__global__ __launch_bounds__(256) void k_final(const ushort* __restrict__ hcp,
                                               const ushort* __restrict__ z3p,
                                               const float* __restrict__ wd2,
                                               const float* __restrict__ bd2,
                                               const float* __restrict__ g3,
                                               const float* __restrict__ be3,
                                               const float* __restrict__ stats3,
                                               const float* __restrict__ catt,
                                               const ushort* __restrict__ wt,
                                               const float* __restrict__ bias,
                                               float* __restrict__ out) {
    __shared__ ushort lds[9616];
    __shared__ float catv[64];
    __shared__ float satt_s[264];     // rows r0-1 .. r0+4, 44 cols
    __shared__ float scv[32], shv[32], wfv[288];
    const int rt = blockIdx.x, og = blockIdx.y, b = blockIdx.z, t = threadIdx.x;
    const int w = t >> 6, lane = t & 63, lr = lane & 15, lg = lane >> 4;
    const int r0 = rt * 4;
    if (t < 64) catv[t] = catt[b*64 + t];
    if (t >= 64 && t < 96) bn_coef(stats3, g3, be3, t - 64, 1.f/28224.f, scv[t-64], shv[t-64]);
    for (int u = t; u < 288; u += 256) {
        int c = u / 9, k = u - c*9;
        wfv[c*9 + k] = wd2[c*9 + 8 - k];
    }
    __syncthreads();
    // inline dconv2: satt rows r0-1..r0+4 (FIX: strided loop, 264 entries > 256 threads)
    for (int u = t; u < 264; u += 256) {
        int syi = u / 44, x = u - syi*44;
        int sy = r0 - 1 + syi;
        if (sy >= 0 && sy < 44) {
            float acc = bd2[0];
            #pragma unroll
            for (int kk = 0; kk < 9; ++kk) {
                int ky = kk / 3, kx = kk - ky*3;
                int ry = sy + ky, rx = x + kx;
                if (ry < 2 || ry > 43 || rx < 2 || rx > 43) continue;
                #pragma unroll
                for (int cg = 0; cg < 4; ++cg) {
                    uint4 raw = *(const uint4*)(z3p + ((((size_t)b*4 + cg)*46 + ry)*48 + rx)*8);
                    unsigned arr[4] = {raw.x, raw.y, raw.z, raw.w};
                    #pragma unroll
                    for (int e = 0; e < 8; ++e) {
                        ushort hv = (e & 1) ? (ushort)(arr[e>>1] >> 16) : (ushort)(arr[e>>1] & 0xffffu);
                        float f = fmaxf(fmaf(bf2f(hv), scv[cg*8 + e], shv[cg*8 + e]), 0.f);
                        acc = fmaf(f, wfv[(cg*8 + e)*9 + kk], acc);
                    }
                }
            }
            satt_s[u] = 1.f / (1.f + expf(-acc));
        }
    }
    f32x4 acc[2][3];
    #pragma unroll
    for (int mf = 0; mf < 2; ++mf)
        #pragma unroll
        for (int nf = 0; nf < 3; ++nf)
            acc[mf][nf] = (f32x4){0.f, 0.f, 0.f, 0.f};

    for (int s = 0; s < 4; ++s) {
        __syncthreads();
        for (int u = t; u < 1200; u += 256) {
            int cg = u / 300, rem = u - cg*300;
            int rr = rem / 50, xx = rem - rr*50;
            int g = s*4 + cg;
            int y1 = r0 + rr;
            uint4 v = {0u,0u,0u,0u};
            if (y1 >= 1 && y1 <= 44 && xx >= 1 && xx <= 44) {   // hcp border (unwritten) -> 0
                int gs = (g < 8) ? g : (g - 8);
                uint4 raw = *(const uint4*)(hcp + (((size_t)(b*8 + gs)*46 + y1)*50 + xx)*8);
                unsigned arr[4] = {raw.x, raw.y, raw.z, raw.w};
                ushort h[8];
                if (g < 8) {
                    float att = satt_s[(y1 - r0)*44 + (xx - 1)];
                    #pragma unroll
                    for (int e = 0; e < 8; ++e) {
                        ushort hv = (e & 1) ? (ushort)(arr[e>>1] >> 16) : (ushort)(arr[e>>1] & 0xffffu);
                        h[e] = f2bf(bf2f(hv) * att);
                    }
                } else {
                    #pragma unroll
                    for (int e = 0; e < 8; ++e) {
                        ushort hv = (e & 1) ? (ushort)(arr[e>>1] >> 16) : (ushort)(arr[e>>1] & 0xffffu);
                        h[e] = f2bf(bf2f(hv) * catv[(g-8)*8 + e]);
                    }
                }
                v.x = h[0] | ((unsigned)h[1] << 16);
                v.y = h[2] | ((unsigned)h[3] << 16);
                v.z = h[4] | ((unsigned)h[5] << 16);
                v.w = h[6] | ((unsigned)h[7] << 16);
            }
            *(uint4*)(lds + (size_t)u*8) = v;
        }
        __syncthreads();
        const int abase = s*32 + lg*8;
        #pragma unroll
        for (int kk = 0; kk < 9; ++kk) {
            bf16x8 af[2];
            #pragma unroll
            for (int mf = 0; mf < 2; ++mf)
                af[mf] = *(const bf16x8*)(wt + (size_t)(kk*64 + og*32 + mf*16 + lr)*128 + abase);
            const int ky = kk / 3, kx = kk - ky*3;
            #pragma unroll
            for (int nf = 0; nf < 3; ++nf) {
                bf16x8 bf = *(const bf16x8*)&lds[((lg*6 + (w + ky))*50 + (nf*16 + lr + kx))*8];
                #pragma unroll
                for (int mf = 0; mf < 2; ++mf)
                    acc[mf][nf] = __builtin_amdgcn_mfma_f32_16x16x32_bf16(af[mf], bf, acc[mf][nf], 0, 0, 0);
            }
        }
    }
    const int y = r0 + w;
    #pragma unroll
    for (int nf = 0; nf < 3; ++nf) {
        int x = nf*16 + lr;
        if (x < 44) {
            #pragma unroll
            for (int mf = 0; mf < 2; ++mf) {
                #pragma unroll
                for (int i = 0; i < 4; ++i) {
                    int o = og*32 + mf*16 + lg*4 + i;
                    out[(((size_t)b*64 + o)*44 + y)*44 + x] = fmaxf(acc[mf][nf][i] + bias[o], 0.f);
                }
            }
        }
    }
}

extern "C" void kernel_launch(void* const* d_in, const int* in_sizes, int n_in,
                              void* d_out, int out_size, void* d_ws, size_t ws_size,
                              hipStream_t stream) {
    const float* depth = (const float*)d_in[0];
    const float* rgb   = (const float*)d_in[1];
    const float* w_hc  = (const float*)d_in[2];
    const float* b_hc  = (const float*)d_in[3];
    const float* w_hf  = (const float*)d_in[4];
    const float* b_hf  = (const float*)d_in[5];
    const float* w_s1  = (const float*)d_in[6];
    const float* bs1   = (const float*)d_in[7];
    const float* g1    = (const float*)d_in[8];
    const float* be1   = (const float*)d_in[9];
    const float* w_s2  = (const float*)d_in[10];
    const float* bs2   = (const float*)d_in[11];
    const float* g2    = (const float*)d_in[12];
    const float* be2   = (const float*)d_in[13];
    const float* w_d1  = (const float*)d_in[14];
    const float* bd1   = (const float*)d_in[15];
    const float* g3    = (const float*)d_in[16];
    const float* be3   = (const float*)d_in[17];
    const float* w_d2  = (const float*)d_in[18];
    const float* bd2   = (const float*)d_in[19];
    const float* w_l1  = (const float*)d_in[20];
    const float* bl1   = (const float*)d_in[21];
    const float* w_l2  = (const float*)d_in[22];
    const float* bl2   = (const float*)d_in[23];

    float* out = (float*)d_out;
    float* ws  = (float*)d_ws;

    float*    catt   = ws;                      // 1,024 f
    float*    dcorp  = catt + 1024;             // 4,096 f  (4 quarters)
    float*    stats  = dcorp + 4096;            // 192 f
    ushort* hcp    = (ushort*)(stats + 192);    // 2,355,200 u  [16][8][46][50][8]
    ushort* wpck   = hcp    + 2355200;          // 147,456 u
    ushort* apck2  = wpck   + 147456;           // 9,216 u
    ushort* apck3  = apck2  + 9216;             // 9,216 u
    ushort* apck1  = apck3  + 9216;             // 562,176 u  [288][1952]
    ushort* depthb = apck1  + 562176;           // 1,998,848 u [16][64][1952]
    ushort* upck   = depthb + 1998848;          // 294,912 u
    ushort* z1p    = upck   + 294912;           // 1,032,192 u
    ushort* z2p    = z1p    + 1032192;          // 1,130,496 u
    ushort* z3p    = z2p    + 1130496;          // 1,130,496 u
    ushort* xpck   = z3p    + 1130496;          // 4,710,400 u

    k_setup<<<3320, 256, 0, stream>>>(w_hc, w_hf, w_s2, w_d1, w_s1, rgb, depth,
                                      wpck, apck2, apck3, apck1, xpck, depthb,
                                      dcorp, stats);

    k_front<<<656, 256, 0, stream>>>(xpck, wpck, b_hc, hcp,
                                     apck1, depthb, upck,
                                     dcorp, w_l1, bl1, w_l2, bl2, catt);

    k_conv1_mfma<<<dim3(11,16), 256, 0, stream>>>(xpck, upck, bs1, z1p, stats);
    k_conv2_mfma<<<dim3(10,16), 256, 0, stream>>>(z1p, apck2, bs2, g1, be1, stats, z2p, stats + 64);
    k_dconv1_mfma<<<dim3(11,16), 256, 0, stream>>>(z2p, apck3, bd1, g2, be2, stats + 64, z3p, stats + 128);

    k_final<<<dim3(11,2,16), 256, 0, stream>>>(hcp, z3p, w_d2, bd2, g3, be3, stats + 128,
                                               catt, wpck + 73728, b_hf, out);
}

// Round 14
// 136.013 us; speedup vs baseline: 1.2856x; 1.2856x over previous
//
#include <hip/hip_runtime.h>
#include <math.h>

#define P_ 1936   // 44*44
#define EPS_ 1e-5f

typedef __attribute__((ext_vector_type(8))) short bf16x8;
typedef __attribute__((ext_vector_type(4))) float f32x4;
typedef __attribute__((ext_vector_type(4))) ushort u16x4;

__device__ __forceinline__ ushort f2bf(float f) {
    union { float f; unsigned u; } v; v.f = f;
    unsigned u = v.u;
    return (ushort)((u + 0x7FFFu + ((u >> 16) & 1u)) >> 16);
}
__device__ __forceinline__ float bf2f(ushort h) {
    union { unsigned u; float f; } v; v.u = (unsigned)h << 16;
    return v.f;
}

__device__ __forceinline__ void bn_coef(const float* stats, const float* g,
                                        const float* be, int ch, float inv_n,
                                        float& sc, float& sh) {
    float sum = stats[ch*2], sq = stats[ch*2+1];
    float mu = sum * inv_n;
    float var = sq * inv_n - mu*mu;
    float r = rsqrtf(var + EPS_);
    sc = g[ch] * r;
    sh = be[ch] - mu * sc;
}

// ---------------- k_setup: weight packs + input prep + zero stats ----------------
__global__ __launch_bounds__(256) void k_setup(const float* __restrict__ whc,
                                               const float* __restrict__ whf,
                                               const float* __restrict__ ws2,
                                               const float* __restrict__ wd1,
                                               const float* __restrict__ ws1,
                                               const float* __restrict__ rgb,
                                               const float* __restrict__ depth,
                                               ushort* __restrict__ wpck,
                                               ushort* __restrict__ a2,
                                               ushort* __restrict__ a3,
                                               ushort* __restrict__ apck1,
                                               ushort* __restrict__ xp,
                                               ushort* __restrict__ depthb,
                                               float* __restrict__ dcor_part,
                                               float* __restrict__ stats) {
    __shared__ float r8[8];
    const int bx = blockIdx.x, t = threadIdx.x;
    if (bx < 2808) {
        if (bx == 0 && t < 192) stats[t] = 0.f;
        int idx = bx * 256 + t;
        if (idx < 147456) {
            const float* src = (idx < 73728) ? whc : whf;
            int j = (idx < 73728) ? idx : idx - 73728;
            int kk = j / 8192, rem = j - kk * 8192;
            int o = rem >> 7, c = rem & 127;
            wpck[(idx < 73728 ? 0 : 73728) + (kk * 64 + o) * 128 + c] =
                f2bf(src[(size_t)(o * 128 + c) * 9 + kk]);
        } else if (idx < 156672) {
            int j = idx - 147456;
            int kk = j >> 10, rem = j & 1023, o = rem >> 5, c = rem & 31;
            a2[j] = f2bf(ws2[((size_t)o*32 + c)*9 + kk]);
            a3[j] = f2bf(wd1[((size_t)c*32 + o)*9 + (8 - kk)]);
        } else if (idx < 718848) {
            int j = idx - 156672;
            int m = j / 1952, p = j - m*1952;
            int o = m / 9, kk = m - o*9;
            apck1[j] = (p < P_) ? f2bf(ws1[((size_t)o*P_ + p)*9 + kk]) : (ushort)0;
        }
        return;
    }
    const int j = bx - 2808;
    const int g8 = j & 7, b = (j >> 3) & 15, q = j >> 7;
    const int c0 = g8 * 8;
    const float* rsrc = rgb   + ((size_t)b*64 + c0)*P_;
    const float* dsrc = depth + ((size_t)b*64 + c0)*P_;
    ushort* xr = xp + ((size_t)(b*16 + g8))*2300*8;
    ushort* xd = xp + ((size_t)(b*16 + 8 + g8))*2300*8;
    if (t < 8) r8[t] = 0.f;
    __syncthreads();
    float dc[8];
    #pragma unroll
    for (int e = 0; e < 8; ++e) dc[e] = 0.f;

    const int pbase = q * 575;
    for (int pos = pbase + t; pos < pbase + 575; pos += 256) {
        int y1 = pos / 50, x1 = pos - y1*50;
        uint4 vr = {0u,0u,0u,0u}, vd = {0u,0u,0u,0u};
        if (y1 >= 1 && y1 <= 44 && x1 >= 1 && x1 <= 44) {
            int p = (y1-1)*44 + (x1-1);
            ushort hr[8], hd[8];
            #pragma unroll
            for (int e = 0; e < 8; ++e) {
                float fr = rsrc[(size_t)e*P_ + p];
                float fd = dsrc[(size_t)e*P_ + p];
                dc[e] = fmaf(fr, fd, dc[e]);
                hr[e] = f2bf(fr); hd[e] = f2bf(fd);
            }
            vr.x = hr[0] | ((unsigned)hr[1] << 16); vr.y = hr[2] | ((unsigned)hr[3] << 16);
            vr.z = hr[4] | ((unsigned)hr[5] << 16); vr.w = hr[6] | ((unsigned)hr[7] << 16);
            vd.x = hd[0] | ((unsigned)hd[1] << 16); vd.y = hd[2] | ((unsigned)hd[3] << 16);
            vd.z = hd[4] | ((unsigned)hd[5] << 16); vd.w = hd[6] | ((unsigned)hd[7] << 16);
        }
        *(uint4*)(xr + (size_t)pos*8) = vr;
        *(uint4*)(xd + (size_t)pos*8) = vd;
    }
    for (int idx = q*976 + t; idx < q*976 + 976; idx += 256) {
        int e = idx / 488, jj = idx - e*488;
        u16x4 h = {0,0,0,0};
        if (jj < 484) {
            float4 f4 = *(const float4*)(dsrc + (size_t)e*P_ + jj*4);
            h[0] = f2bf(f4.x); h[1] = f2bf(f4.y); h[2] = f2bf(f4.z); h[3] = f2bf(f4.w);
        }
        *(u16x4*)(depthb + ((size_t)(b*64 + c0 + e))*1952 + jj*4) = h;
    }
    #pragma unroll
    for (int e = 0; e < 8; ++e) {
        float v = dc[e];
        #pragma unroll
        for (int off = 32; off > 0; off >>= 1) v += __shfl_down(v, off, 64);
        if ((t & 63) == 0) atomicAdd(&r8[e], v);
    }
    __syncthreads();
    if (t < 8) dcor_part[q*1024 + b*64 + c0 + t] = r8[t];
}

// ---------------- k_front: hcconv og-split (352) + Umfma (288) + MLP (16) ----------------
__global__ __launch_bounds__(256) void k_front(const ushort* __restrict__ xp,
                                               const ushort* __restrict__ wt,
                                               const float* __restrict__ bhc,
                                               ushort* __restrict__ hcp,
                                               const ushort* __restrict__ apck1,
                                               const ushort* __restrict__ depthb,
                                               ushort* __restrict__ upck,
                                               const float* __restrict__ dcor_part,
                                               const float* __restrict__ wl1,
                                               const float* __restrict__ bl1,
                                               const float* __restrict__ wl2,
                                               const float* __restrict__ bl2,
                                               float* __restrict__ catt) {
    __shared__ ushort lds[9616];
    __shared__ float mlpb[80];
    const int bx = blockIdx.x, t = threadIdx.x;
    if (bx < 352) {
        // hc conv, og from block index (352 blocks for parallelism)
        const int rt = bx % 11, og = (bx / 11) & 1, b = bx / 22;
        const int w = t >> 6, lane = t & 63, lr = lane & 15, lg = lane >> 4;
        const int r0 = rt * 4;
        f32x4 acc[2][3];
        #pragma unroll
        for (int mf = 0; mf < 2; ++mf)
            #pragma unroll
            for (int nf = 0; nf < 3; ++nf)
                acc[mf][nf] = (f32x4){0.f, 0.f, 0.f, 0.f};

        for (int s = 0; s < 4; ++s) {
            __syncthreads();
            const ushort* gsrc = xp + ((size_t)(b*16 + s*4))*2300*8;
            for (int u = t; u < 1200; u += 256) {
                int cg = u / 300, rem = u - cg*300;
                int rr = rem / 50, xx = rem - rr*50;
                uint4 v = *(const uint4*)(gsrc + (((size_t)cg*46 + (r0+rr))*50 + xx)*8);
                *(uint4*)(lds + (size_t)u*8) = v;
            }
            __syncthreads();
            const int abase = s*32 + lg*8;
            #pragma unroll
            for (int kk = 0; kk < 9; ++kk) {
                bf16x8 af[2];
                #pragma unroll
                for (int mf = 0; mf < 2; ++mf)
                    af[mf] = *(const bf16x8*)(wt + (size_t)(kk*64 + og*32 + mf*16 + lr)*128 + abase);
                const int ky = kk / 3, kx = kk - ky*3;
                #pragma unroll
                for (int nf = 0; nf < 3; ++nf) {
                    bf16x8 bf = *(const bf16x8*)&lds[((lg*6 + (w + ky))*50 + (nf*16 + lr + kx))*8];
                    #pragma unroll
                    for (int mf = 0; mf < 2; ++mf)
                        acc[mf][nf] = __builtin_amdgcn_mfma_f32_16x16x32_bf16(af[mf], bf, acc[mf][nf], 0, 0, 0);
                }
            }
        }
        const int y = r0 + w;
        #pragma unroll
        for (int nf = 0; nf < 3; ++nf) {
            int x = nf*16 + lr;
            if (x < 44) {
                #pragma unroll
                for (int mf = 0; mf < 2; ++mf) {
                    u16x4 pk;
                    #pragma unroll
                    for (int i = 0; i < 4; ++i) {
                        int ol = og*32 + mf*16 + lg*4 + i;
                        pk[i] = f2bf(fmaxf(acc[mf][nf][i] + bhc[ol], 0.f));
                    }
                    int g = og*4 + mf*2 + (lg >> 1);
                    *(u16x4*)(hcp + (((size_t)(b*8 + g)*46 + (y+1))*50 + (x+1))*8 + (lg&1)*4) = pk;
                }
            }
        }
        return;
    }
    const int j = bx - 352;
    const int mt = j % 19, b = j / 19;
    if (mt == 18) {
        float* dcs = mlpb;       // 64
        float* h   = mlpb + 64;  // 16
        if (t < 64) dcs[t] = dcor_part[b*64 + t] + dcor_part[1024 + b*64 + t]
                           + dcor_part[2048 + b*64 + t] + dcor_part[3072 + b*64 + t];
        __syncthreads();
        if (t < 16) {
            float a = bl1[t];
            #pragma unroll 8
            for (int c = 0; c < 64; ++c) a = fmaf(dcs[c], wl1[t*64 + c], a);
            h[t] = fmaxf(a, 0.f);
        }
        __syncthreads();
        if (t < 64) {
            float m = bl2[t];
            #pragma unroll
            for (int jj = 0; jj < 16; ++jj) m = fmaf(h[jj], wl2[t*16 + jj], m);
            catt[b*64 + t] = 1.f / (1.f + expf(-2.f*m));
        }
        return;
    }
    const int nt = t >> 6, lane = t & 63, lr = lane & 15, lg = lane >> 4;
    f32x4 acc = (f32x4){0.f, 0.f, 0.f, 0.f};
    const ushort* ap = apck1 + (size_t)(mt*16 + lr)*1952 + lg*8;
    const ushort* bp = depthb + ((size_t)(b*64) + nt*16 + lr)*1952 + lg*8;
    #pragma unroll 4
    for (int ks = 0; ks < 61; ++ks) {
        bf16x8 af = *(const bf16x8*)(ap + ks*32);
        bf16x8 bf = *(const bf16x8*)(bp + ks*32);
        acc = __builtin_amdgcn_mfma_f32_16x16x32_bf16(af, bf, acc, 0, 0, 0);
    }
    #pragma unroll
    for (int i = 0; i < 4; ++i) {
        int m = mt*16 + lg*4 + i;
        int o = m / 9, kk = m - o*9;
        upck[((size_t)(b*9 + kk)*32 + o)*64 + nt*16 + lr] = f2bf(acc[i]);
    }
}

// ---------------- conv1 MFMA: rgb(64ch) x U -> z1p bf16 [b][cg4][42][48][8] + stats ----------------
__global__ __launch_bounds__(256) void k_conv1_mfma(const ushort* __restrict__ xp,
                                                    const ushort* __restrict__ upck,
                                                    const float* __restrict__ bs1,
                                                    ushort* __restrict__ z1p,
                                                    float* __restrict__ stats) {
    __shared__ ushort lds[8*6*50*8 + 32];
    __shared__ float ssum[32], ssq[32];
    const int rt = blockIdx.x, b = blockIdx.y, t = threadIdx.x;
    const int w = t >> 6, lane = t & 63, lr = lane & 15, lg = lane >> 4;
    const int r0 = rt * 4;
    if (t < 32) { ssum[t] = 0.f; ssq[t] = 0.f; }
    f32x4 acc[2][3];
    #pragma unroll
    for (int mf = 0; mf < 2; ++mf)
        #pragma unroll
        for (int nf = 0; nf < 3; ++nf)
            acc[mf][nf] = (f32x4){0.f, 0.f, 0.f, 0.f};

    const ushort* gsrc = xp + (size_t)b*16*2300*8;   // rgb groups 0..7
    for (int u = t; u < 2400; u += 256) {
        int cg = u / 300, rem = u - cg*300;
        int rr = rem / 50, xx = rem - rr*50;
        int y1 = min(r0 + 1 + rr, 45);
        *(uint4*)(lds + (size_t)u*8) = *(const uint4*)(gsrc + (((size_t)cg*46 + y1)*50 + xx)*8);
    }
    __syncthreads();
    #pragma unroll
    for (int s = 0; s < 2; ++s) {
        #pragma unroll
        for (int kk = 0; kk < 9; ++kk) {
            bf16x8 af[2];
            #pragma unroll
            for (int mf = 0; mf < 2; ++mf)
                af[mf] = *(const bf16x8*)(upck + ((size_t)(b*9 + kk)*32 + mf*16 + lr)*64 + s*32 + lg*8);
            const int ky = kk / 3, kx = kk - ky*3;
            #pragma unroll
            for (int nf = 0; nf < 3; ++nf) {
                bf16x8 bv = *(const bf16x8*)&lds[(((s*4 + lg)*6 + (w + ky))*50 + (nf*16 + lr + kx + 1))*8];
                #pragma unroll
                for (int mf = 0; mf < 2; ++mf)
                    acc[mf][nf] = __builtin_amdgcn_mfma_f32_16x16x32_bf16(af[mf], bv, acc[mf][nf], 0, 0, 0);
            }
        }
    }
    const int y = r0 + w;
    const int cb = lg*4;
    if (y < 42) {
        float ls[2][4], lq[2][4], br[2][4];
        #pragma unroll
        for (int mf = 0; mf < 2; ++mf)
            #pragma unroll
            for (int i = 0; i < 4; ++i) {
                ls[mf][i] = 0.f; lq[mf][i] = 0.f;
                br[mf][i] = bs1[mf*16 + cb + i];
            }
        #pragma unroll
        for (int nf = 0; nf < 3; ++nf) {
            int x = nf*16 + lr;
            bool xv = (x < 42);
            #pragma unroll
            for (int mf = 0; mf < 2; ++mf) {
                u16x4 pk;
                #pragma unroll
                for (int i = 0; i < 4; ++i) {
                    float v = acc[mf][nf][i] + br[mf][i];
                    if (xv) { ls[mf][i] += v; lq[mf][i] = fmaf(v, v, lq[mf][i]); }
                    pk[i] = f2bf(v);
                }
                if (xv) {
                    int cg1 = mf*2 + (lg >> 1);
                    *(u16x4*)(z1p + ((((size_t)b*4 + cg1)*42 + y)*48 + x)*8 + (lg&1)*4) = pk;
                }
            }
        }
        #pragma unroll
        for (int mf = 0; mf < 2; ++mf)
            #pragma unroll
            for (int i = 0; i < 4; ++i) {
                float s0 = ls[mf][i], q0 = lq[mf][i];
                #pragma unroll
                for (int m = 1; m < 16; m <<= 1) { s0 += __shfl_xor(s0, m, 64); q0 += __shfl_xor(q0, m, 64); }
                if (lr == 0) { atomicAdd(&ssum[mf*16 + cb + i], s0); atomicAdd(&ssq[mf*16 + cb + i], q0); }
            }
    }
    __syncthreads();
    if (t < 32) { atomicAdd(&stats[t*2], ssum[t]); atomicAdd(&stats[t*2+1], ssq[t]); }
}

// ---------------- conv2 MFMA: relu(bn1(z1)) x ws2 -> z2p bf16 padded [b][cg4][46][48][8] + stats ----------------
__global__ __launch_bounds__(256) void k_conv2_mfma(const ushort* __restrict__ z1p,
                                                    const ushort* __restrict__ apck,
                                                    const float* __restrict__ bs2,
                                                    const float* __restrict__ g1,
                                                    const float* __restrict__ be1,
                                                    const float* __restrict__ statsIn,
                                                    ushort* __restrict__ z2p,
                                                    float* __restrict__ statsOut) {
    __shared__ ushort lds[4*6*48*8 + 32];
    __shared__ float sc[32], sh[32], ssum[32], ssq[32];
    const int rt = blockIdx.x, b = blockIdx.y, t = threadIdx.x;
    const int w = t >> 6, lane = t & 63, lr = lane & 15, lg = lane >> 4;
    const int r0 = rt * 4;
    if (t < 32) {
        bn_coef(statsIn, g1, be1, t, 1.f/28224.f, sc[t], sh[t]);
        ssum[t] = 0.f; ssq[t] = 0.f;
    }
    __syncthreads();
    f32x4 acc[2][3];
    #pragma unroll
    for (int mf = 0; mf < 2; ++mf)
        #pragma unroll
        for (int nf = 0; nf < 3; ++nf)
            acc[mf][nf] = (f32x4){0.f, 0.f, 0.f, 0.f};

    for (int u = t; u < 1152; u += 256) {
        int cg = u / 288, rem = u - cg*288;
        int rr = rem / 48, xx = rem - rr*48;
        uint4 raw = *(const uint4*)(z1p + ((((size_t)b*4 + cg)*42 + (r0 + rr))*48 + xx)*8);
        unsigned arr[4] = {raw.x, raw.y, raw.z, raw.w};
        ushort h[8];
        #pragma unroll
        for (int e = 0; e < 8; ++e) {
            ushort hv = (e & 1) ? (ushort)(arr[e>>1] >> 16) : (ushort)(arr[e>>1] & 0xffffu);
            float f = fmaxf(fmaf(bf2f(hv), sc[cg*8 + e], sh[cg*8 + e]), 0.f);
            h[e] = f2bf(f);
        }
        uint4 v;
        v.x = h[0] | ((unsigned)h[1] << 16);
        v.y = h[2] | ((unsigned)h[3] << 16);
        v.z = h[4] | ((unsigned)h[5] << 16);
        v.w = h[6] | ((unsigned)h[7] << 16);
        *(uint4*)(lds + (size_t)u*8) = v;
    }
    __syncthreads();
    #pragma unroll
    for (int kk = 0; kk < 9; ++kk) {
        bf16x8 af[2];
        #pragma unroll
        for (int mf = 0; mf < 2; ++mf)
            af[mf] = *(const bf16x8*)(apck + (size_t)(kk*32 + mf*16 + lr)*32 + lg*8);
        const int ky = kk / 3, kx = kk - ky*3;
        #pragma unroll
        for (int nf = 0; nf < 3; ++nf) {
            bf16x8 bv = *(const bf16x8*)&lds[((lg*6 + (w + ky))*48 + (nf*16 + lr + kx))*8];
            #pragma unroll
            for (int mf = 0; mf < 2; ++mf)
                acc[mf][nf] = __builtin_amdgcn_mfma_f32_16x16x32_bf16(af[mf], bv, acc[mf][nf], 0, 0, 0);
        }
    }
    const int y = r0 + w;   // 0..39
    const int cb = lg*4;
    {
        float ls[2][4], lq[2][4], br[2][4];
        #pragma unroll
        for (int mf = 0; mf < 2; ++mf)
            #pragma unroll
            for (int i = 0; i < 4; ++i) {
                ls[mf][i] = 0.f; lq[mf][i] = 0.f;
                br[mf][i] = bs2[mf*16 + cb + i];
            }
        #pragma unroll
        for (int nf = 0; nf < 3; ++nf) {
            int x = nf*16 + lr;
            bool xv = (x < 40);
            #pragma unroll
            for (int mf = 0; mf < 2; ++mf) {
                u16x4 pk;
                #pragma unroll
                for (int i = 0; i < 4; ++i) {
                    float v = acc[mf][nf][i] + br[mf][i];
                    if (xv) { ls[mf][i] += v; lq[mf][i] = fmaf(v, v, lq[mf][i]); }
                    pk[i] = f2bf(v);
                }
                if (xv) {
                    int cg1 = mf*2 + (lg >> 1);
                    *(u16x4*)(z2p + ((((size_t)b*4 + cg1)*46 + (y+2))*48 + (x+2))*8 + (lg&1)*4) = pk;
                }
            }
        }
        #pragma unroll
        for (int mf = 0; mf < 2; ++mf)
            #pragma unroll
            for (int i = 0; i < 4; ++i) {
                float s0 = ls[mf][i], q0 = lq[mf][i];
                #pragma unroll
                for (int m = 1; m < 16; m <<= 1) { s0 += __shfl_xor(s0, m, 64); q0 += __shfl_xor(q0, m, 64); }
                if (lr == 0) { atomicAdd(&ssum[mf*16 + cb + i], s0); atomicAdd(&ssq[mf*16 + cb + i], q0); }
            }
    }
    __syncthreads();
    if (t < 32) { atomicAdd(&statsOut[t*2], ssum[t]); atomicAdd(&statsOut[t*2+1], ssq[t]); }
}

// ---------------- dconv1 MFMA: relu(bn2(z2)) *T wd1 -> z3p bf16 padded + stats ----------------
__global__ __launch_bounds__(256) void k_dconv1_mfma(const ushort* __restrict__ z2p,
                                                     const ushort* __restrict__ apck,
                                                     const float* __restrict__ bd1,
                                                     const float* __restrict__ g2,
                                                     const float* __restrict__ be2,
                                                     const float* __restrict__ statsIn,
                                                     ushort* __restrict__ z3p,
                                                     float* __restrict__ statsOut) {
    __shared__ ushort lds[4*6*48*8 + 32];
    __shared__ float sc[32], sh[32], ssum[32], ssq[32];
    const int rt = blockIdx.x, b = blockIdx.y, t = threadIdx.x;
    const int w = t >> 6, lane = t & 63, lr = lane & 15, lg = lane >> 4;
    const int r0 = rt * 4;
    if (t < 32) {
        bn_coef(statsIn, g2, be2, t, 1.f/25600.f, sc[t], sh[t]);
        ssum[t] = 0.f; ssq[t] = 0.f;
    }
    __syncthreads();
    f32x4 acc[2][3];
    #pragma unroll
    for (int mf = 0; mf < 2; ++mf)
        #pragma unroll
        for (int nf = 0; nf < 3; ++nf)
            acc[mf][nf] = (f32x4){0.f, 0.f, 0.f, 0.f};

    for (int u = t; u < 1152; u += 256) {
        int cg = u / 288, rem = u - cg*288;
        int rr = rem / 48, xx = rem - rr*48;
        int row = r0 + rr;
        uint4 v = {0u,0u,0u,0u};
        if (row >= 2 && row <= 41 && xx >= 2 && xx <= 41) {
            uint4 raw = *(const uint4*)(z2p + ((((size_t)b*4 + cg)*46 + row)*48 + xx)*8);
            unsigned arr[4] = {raw.x, raw.y, raw.z, raw.w};
            ushort h[8];
            #pragma unroll
            for (int e = 0; e < 8; ++e) {
                ushort hv = (e & 1) ? (ushort)(arr[e>>1] >> 16) : (ushort)(arr[e>>1] & 0xffffu);
                float f = fmaxf(fmaf(bf2f(hv), sc[cg*8 + e], sh[cg*8 + e]), 0.f);
                h[e] = f2bf(f);
            }
            v.x = h[0] | ((unsigned)h[1] << 16);
            v.y = h[2] | ((unsigned)h[3] << 16);
            v.z = h[4] | ((unsigned)h[5] << 16);
            v.w = h[6] | ((unsigned)h[7] << 16);
        }
        *(uint4*)(lds + (size_t)u*8) = v;
    }
    __syncthreads();
    #pragma unroll
    for (int kk = 0; kk < 9; ++kk) {
        bf16x8 af[2];
        #pragma unroll
        for (int mf = 0; mf < 2; ++mf)
            af[mf] = *(const bf16x8*)(apck + (size_t)(kk*32 + mf*16 + lr)*32 + lg*8);
        const int ky = kk / 3, kx = kk - ky*3;
        #pragma unroll
        for (int nf = 0; nf < 3; ++nf) {
            bf16x8 bv = *(const bf16x8*)&lds[((lg*6 + (w + ky))*48 + (nf*16 + lr + kx))*8];
            #pragma unroll
            for (int mf = 0; mf < 2; ++mf)
                acc[mf][nf] = __builtin_amdgcn_mfma_f32_16x16x32_bf16(af[mf], bv, acc[mf][nf], 0, 0, 0);
        }
    }
    const int y = r0 + w;
    const int cb = lg*4;
    if (y < 42) {
        float ls[2][4], lq[2][4], br[2][4];
        #pragma unroll
        for (int mf = 0; mf < 2; ++mf)
            #pragma unroll
            for (int i = 0; i < 4; ++i) {
                ls[mf][i] = 0.f; lq[mf][i] = 0.f;
                br[mf][i] = bd1[mf*16 + cb + i];
            }
        #pragma unroll
        for (int nf = 0; nf < 3; ++nf) {
            int x = nf*16 + lr;
            bool xv = (x < 42);
            #pragma unroll
            for (int mf = 0; mf < 2; ++mf) {
                u16x4 pk;
                #pragma unroll
                for (int i = 0; i < 4; ++i) {
                    float v = acc[mf][nf][i] + br[mf][i];
                    if (xv) { ls[mf][i] += v; lq[mf][i] = fmaf(v, v, lq[mf][i]); }
                    pk[i] = f2bf(v);
                }
                if (xv) {
                    int cg1 = mf*2 + (lg >> 1);
                    *(u16x4*)(z3p + ((((size_t)b*4 + cg1)*46 + (y+2))*48 + (x+2))*8 + (lg&1)*4) = pk;
                }
            }
        }
        #pragma unroll
        for (int mf = 0; mf < 2; ++mf)
            #pragma unroll
            for (int i = 0; i < 4; ++i) {
                float s0 = ls[mf][i], q0 = lq[mf][i];
                #pragma unroll
                for (int m = 1; m < 16; m <<= 1) { s0 += __shfl_xor(s0, m, 64); q0 += __shfl_xor(q0, m, 64); }
                if (lr == 0) { atomicAdd(&ssum[mf*16 + cb + i], s0); atomicAdd(&ssq[mf*16 + cb + i], q0); }
            }
    }
    __syncthreads();
    if (t < 32) { atomicAdd(&statsOut[t*2], ssum[t]); atomicAdd(&statsOut[t*2+1], ssq[t]); }
}

// ---------------- dconv2: relu(bn3(z3)) *T wd2 -> sigmoid -> satt ----------------
__global__ __launch_bounds__(256) void k_dconv2(const ushort* __restrict__ z3p,
                                                const float* __restrict__ wd2,
                                                const float* __restrict__ bd2,
                                                const float* __restrict__ g3,
                                                const float* __restrict__ be3,
                                                const float* __restrict__ stats,
                                                float* __restrict__ satt) {
    __shared__ float sc[32], sh[32], wf[32][9];
    const int b = blockIdx.y, t = threadIdx.x;
    if (t < 32) bn_coef(stats, g3, be3, t, 1.f/28224.f, sc[t], sh[t]);
    for (int u = t; u < 288; u += 256) {
        int c = u / 9, k = u - c*9;
        wf[c][k] = wd2[c*9 + 8 - k];
    }
    __syncthreads();
    const int pix = blockIdx.x * 256 + t;
    if (pix >= P_) return;
    const int y = pix / 44, x = pix - y*44;
    float acc = bd2[0];
    #pragma unroll
    for (int kk = 0; kk < 9; ++kk) {
        int ky = kk / 3, kx = kk - ky*3;
        int ry = y + ky, rx = x + kx;
        if (ry < 2 || ry > 43 || rx < 2 || rx > 43) continue;
        #pragma unroll
        for (int cg = 0; cg < 4; ++cg) {
            uint4 raw = *(const uint4*)(z3p + ((((size_t)b*4 + cg)*46 + ry)*48 + rx)*8);
            unsigned arr[4] = {raw.x, raw.y, raw.z, raw.w};
            #pragma unroll
            for (int e = 0; e < 8; ++e) {
                ushort hv = (e & 1) ? (ushort)(arr[e>>1] >> 16) : (ushort)(arr[e>>1] & 0xffffu);
                float f = fmaxf(fmaf(bf2f(hv), sc[cg*8 + e], sh[cg*8 + e]), 0.f);
                acc = fmaf(f, wf[cg*8 + e][kk], acc);
            }
        }
    }
    satt[(size_t)b*P_ + pix] = 1.f / (1.f + expf(-acc));
}

// ---------------- final conv MFMA: h_att (built in staging, guarded borders) -> out f32 ----------------
__global__ __launch_bounds__(256) void k_final(const ushort* __restrict__ hcp,
                                               const float* __restrict__ satt,
                                               const float* __restrict__ catt,
                                               const ushort* __restrict__ wt,
                                               const float* __restrict__ bias,
                                               float* __restrict__ out) {
    __shared__ ushort lds[9616];
    __shared__ float catv[64];
    const int rt = blockIdx.x, og = blockIdx.y, b = blockIdx.z, t = threadIdx.x;
    const int w = t >> 6, lane = t & 63, lr = lane & 15, lg = lane >> 4;
    const int r0 = rt * 4;
    if (t < 64) catv[t] = catt[b*64 + t];
    f32x4 acc[2][3];
    #pragma unroll
    for (int mf = 0; mf < 2; ++mf)
        #pragma unroll
        for (int nf = 0; nf < 3; ++nf)
            acc[mf][nf] = (f32x4){0.f, 0.f, 0.f, 0.f};

    for (int s = 0; s < 4; ++s) {
        __syncthreads();
        for (int u = t; u < 1200; u += 256) {
            int cg = u / 300, rem = u - cg*300;
            int rr = rem / 50, xx = rem - rr*50;
            int g = s*4 + cg;
            int y1 = r0 + rr;
            uint4 v = {0u,0u,0u,0u};
            if (y1 >= 1 && y1 <= 44 && xx >= 1 && xx <= 44) {   // hcp border (unwritten) -> 0
                int gs = (g < 8) ? g : (g - 8);
                uint4 raw = *(const uint4*)(hcp + (((size_t)(b*8 + gs)*46 + y1)*50 + xx)*8);
                unsigned arr[4] = {raw.x, raw.y, raw.z, raw.w};
                ushort h[8];
                if (g < 8) {
                    float att = satt[(size_t)b*P_ + (y1-1)*44 + (xx-1)];
                    #pragma unroll
                    for (int e = 0; e < 8; ++e) {
                        ushort hv = (e & 1) ? (ushort)(arr[e>>1] >> 16) : (ushort)(arr[e>>1] & 0xffffu);
                        h[e] = f2bf(bf2f(hv) * att);
                    }
                } else {
                    #pragma unroll
                    for (int e = 0; e < 8; ++e) {
                        ushort hv = (e & 1) ? (ushort)(arr[e>>1] >> 16) : (ushort)(arr[e>>1] & 0xffffu);
                        h[e] = f2bf(bf2f(hv) * catv[(g-8)*8 + e]);
                    }
                }
                v.x = h[0] | ((unsigned)h[1] << 16);
                v.y = h[2] | ((unsigned)h[3] << 16);
                v.z = h[4] | ((unsigned)h[5] << 16);
                v.w = h[6] | ((unsigned)h[7] << 16);
            }
            *(uint4*)(lds + (size_t)u*8) = v;
        }
        __syncthreads();
        const int abase = s*32 + lg*8;
        #pragma unroll
        for (int kk = 0; kk < 9; ++kk) {
            bf16x8 af[2];
            #pragma unroll
            for (int mf = 0; mf < 2; ++mf)
                af[mf] = *(const bf16x8*)(wt + (size_t)(kk*64 + og*32 + mf*16 + lr)*128 + abase);
            const int ky = kk / 3, kx = kk - ky*3;
            #pragma unroll
            for (int nf = 0; nf < 3; ++nf) {
                bf16x8 bf = *(const bf16x8*)&lds[((lg*6 + (w + ky))*50 + (nf*16 + lr + kx))*8];
                #pragma unroll
                for (int mf = 0; mf < 2; ++mf)
                    acc[mf][nf] = __builtin_amdgcn_mfma_f32_16x16x32_bf16(af[mf], bf, acc[mf][nf], 0, 0, 0);
            }
        }
    }
    const int y = r0 + w;
    #pragma unroll
    for (int nf = 0; nf < 3; ++nf) {
        int x = nf*16 + lr;
        if (x < 44) {
            #pragma unroll
            for (int mf = 0; mf < 2; ++mf) {
                #pragma unroll
                for (int i = 0; i < 4; ++i) {
                    int o = og*32 + mf*16 + lg*4 + i;
                    out[(((size_t)b*64 + o)*44 + y)*44 + x] = fmaxf(acc[mf][nf][i] + bias[o], 0.f);
                }
            }
        }
    }
}

extern "C" void kernel_launch(void* const* d_in, const int* in_sizes, int n_in,
                              void* d_out, int out_size, void* d_ws, size_t ws_size,
                              hipStream_t stream) {
    const float* depth = (const float*)d_in[0];
    const float* rgb   = (const float*)d_in[1];
    const float* w_hc  = (const float*)d_in[2];
    const float* b_hc  = (const float*)d_in[3];
    const float* w_hf  = (const float*)d_in[4];
    const float* b_hf  = (const float*)d_in[5];
    const float* w_s1  = (const float*)d_in[6];
    const float* bs1   = (const float*)d_in[7];
    const float* g1    = (const float*)d_in[8];
    const float* be1   = (const float*)d_in[9];
    const float* w_s2  = (const float*)d_in[10];
    const float* bs2   = (const float*)d_in[11];
    const float* g2    = (const float*)d_in[12];
    const float* be2   = (const float*)d_in[13];
    const float* w_d1  = (const float*)d_in[14];
    const float* bd1   = (const float*)d_in[15];
    const float* g3    = (const float*)d_in[16];
    const float* be3   = (const float*)d_in[17];
    const float* w_d2  = (const float*)d_in[18];
    const float* bd2   = (const float*)d_in[19];
    const float* w_l1  = (const float*)d_in[20];
    const float* bl1   = (const float*)d_in[21];
    const float* w_l2  = (const float*)d_in[22];
    const float* bl2   = (const float*)d_in[23];

    float* out = (float*)d_out;
    float* ws  = (float*)d_ws;

    float*    satt   = ws;                      // 30,976 f
    float*    catt   = satt + 30976;            // 1,024 f
    float*    dcorp  = catt + 1024;             // 4,096 f  (4 quarters)
    float*    stats  = dcorp + 4096;            // 192 f
    ushort* hcp    = (ushort*)(stats + 192);    // 2,355,200 u  [16][8][46][50][8]
    ushort* wpck   = hcp    + 2355200;          // 147,456 u
    ushort* apck2  = wpck   + 147456;           // 9,216 u
    ushort* apck3  = apck2  + 9216;             // 9,216 u
    ushort* apck1  = apck3  + 9216;             // 562,176 u  [288][1952]
    ushort* depthb = apck1  + 562176;           // 1,998,848 u [16][64][1952]
    ushort* upck   = depthb + 1998848;          // 294,912 u
    ushort* z1p    = upck   + 294912;           // 1,032,192 u
    ushort* z2p    = z1p    + 1032192;          // 1,130,496 u
    ushort* z3p    = z2p    + 1130496;          // 1,130,496 u
    ushort* xpck   = z3p    + 1130496;          // 4,710,400 u

    k_setup<<<3320, 256, 0, stream>>>(w_hc, w_hf, w_s2, w_d1, w_s1, rgb, depth,
                                      wpck, apck2, apck3, apck1, xpck, depthb,
                                      dcorp, stats);

    k_front<<<656, 256, 0, stream>>>(xpck, wpck, b_hc, hcp,
                                     apck1, depthb, upck,
                                     dcorp, w_l1, bl1, w_l2, bl2, catt);

    k_conv1_mfma<<<dim3(11,16), 256, 0, stream>>>(xpck, upck, bs1, z1p, stats);
    k_conv2_mfma<<<dim3(10,16), 256, 0, stream>>>(z1p, apck2, bs2, g1, be1, stats, z2p, stats + 64);
    k_dconv1_mfma<<<dim3(11,16), 256, 0, stream>>>(z2p, apck3, bd1, g2, be2, stats + 64, z3p, stats + 128);
    k_dconv2<<<dim3(8,16), 256, 0, stream>>>(z3p, w_d2, bd2, g3, be3, stats + 128, satt);

    k_final<<<dim3(11,2,16), 256, 0, stream>>>(hcp, satt, catt, wpck + 73728, b_hf, out);
}